// Round 8
// baseline (618.851 us; speedup 1.0000x reference)
//
#include <hip/hip_runtime.h>
#include <math.h>

#define CCH 128
#define G3  384
#define BN_EPS 1e-5f
#define BSH 9              // bucket shift: 512 rows/bucket
#define BROWS 512
#define COLBITS 19         // col < 2^19 (N=200000); row-in-bucket packed above

typedef __bf16 bf16;
typedef __bf16 bf16x2 __attribute__((ext_vector_type(2)));
typedef __bf16 bf16x4 __attribute__((ext_vector_type(4)));
typedef __bf16 bf16x8 __attribute__((ext_vector_type(8)));
typedef float f32x4 __attribute__((ext_vector_type(4)));

// ---------------- fused prep kernel (block-range roles) ----------------
// [0,B1): bn fold  [B1,B2): gat matvec  [B2,B3): bounds tt  [B3,B4): bounds mol
// [B4,B5): zero bhist  [B5..B9): W repack fp32 -> bf16 MFMA-fragment layout:
//   per 128-col block bi: chunk (kc in 0..15, nrow in 0..127) of 8 bf16 at
//   dst[bi*16384 + (kc*128 + nrow)*8] = W[bi*128+nrow][kc*8 .. +8]
__global__ __launch_bounds__(256) void prep_kernel(
    const float* __restrict__ g, const float* __restrict__ b,
    const float* __restrict__ m, const float* __restrict__ v,
    float* __restrict__ bnsc, float* __restrict__ bnsh,
    const float* __restrict__ Wsrc, const float* __restrict__ Wdst,
    const float* __restrict__ asrc, const float* __restrict__ adst,
    float* __restrict__ vsp, float* __restrict__ vd, float* __restrict__ c0,
    const int* __restrict__ tt_node_batch, int N, int NTT, int* __restrict__ starts_tt,
    const int* __restrict__ tt_graph_batch, int NMOL, int* __restrict__ starts_mol,
    int* __restrict__ bhist,
    const float* __restrict__ Wgcn, bf16* __restrict__ Wgcnb,
    bf16* __restrict__ Wsrcb,
    const float* __restrict__ Wih, bf16* __restrict__ Wihb,
    const float* __restrict__ Whh, bf16* __restrict__ Whhb,
    int B1, int B2, int B3, int B4, int B5, int B6, int B7, int B8)
{
    __shared__ float red[2];
    const int bid = blockIdx.x;
    const int tid = threadIdx.x;
    if (bid < B1) {
        int idx = bid * 256 + tid;
        if (idx < 8 * CCH) {
            float s = g[idx] / sqrtf(v[idx] + BN_EPS);
            bnsc[idx] = s;
            bnsh[idx] = b[idx] - m[idx] * s;
        }
    } else if (bid < B2) {
        int s = bid - B1;
        int which = tid >> 7, k = tid & 127;
        const float* W = (which ? Wdst : Wsrc) + s * CCH * CCH;
        const float* a = (which ? adst : asrc) + s * CCH;
        float acc = 0.f;
        for (int j = 0; j < CCH; ++j) acc += W[j * CCH + k] * a[j];
        if (which) {
            vd[s * CCH + k] = acc;
        } else {
            int l = 2 + 3 * s;
            float scl = g[l * CCH + k] / sqrtf(v[l * CCH + k] + BN_EPS);
            float shf = b[l * CCH + k] - m[l * CCH + k] * scl;
            vsp[s * CCH + k] = acc * scl;
            float p = shf * acc;
            for (int o = 32; o; o >>= 1) p += __shfl_down(p, o);
            if ((k & 63) == 0) red[k >> 6] = p;
        }
        __syncthreads();
        if (tid == 0) c0[s] = red[0] + red[1];
    } else if (bid < B3) {
        int s = (bid - B2) * 256 + tid;
        if (s <= NTT) {
            int lo = 0, hi = N;
            while (lo < hi) { int mid = (lo + hi) >> 1; if (tt_node_batch[mid] < s) lo = mid + 1; else hi = mid; }
            starts_tt[s] = lo;
        }
    } else if (bid < B4) {
        int s = (bid - B3) * 256 + tid;
        if (s <= NMOL) {
            int lo = 0, hi = NTT;
            while (lo < hi) { int mid = (lo + hi) >> 1; if (tt_graph_batch[mid] < s) lo = mid + 1; else hi = mid; }
            starts_mol[s] = lo;
        }
    } else if (bid < B5) {
        bhist[tid] = 0; bhist[tid + 256] = 0;
    } else {
        const float* src; bf16* dst; int u0;
        if (bid < B6)      { src = Wgcn; dst = Wgcnb; u0 = (bid - B5) * 256; }
        else if (bid < B7) { src = Wsrc; dst = Wsrcb; u0 = (bid - B6) * 256; }
        else if (bid < B8) { src = Wih;  dst = Wihb;  u0 = (bid - B7) * 256; }
        else               { src = Whh;  dst = Whhb;  u0 = (bid - B8) * 256; }
        int u = u0 + tid;
        int row = u >> 4, kc = u & 15;
        int bi = row >> 7, nrow = row & 127;
        const float* s = src + (size_t)row * CCH + kc * 8;
        float4 a = *(const float4*)s;
        float4 b4 = *(const float4*)(s + 4);
        bf16x8 o = { (bf16)a.x, (bf16)a.y, (bf16)a.z, (bf16)a.w,
                     (bf16)b4.x, (bf16)b4.y, (bf16)b4.z, (bf16)b4.w };
        *(bf16x8*)&dst[(size_t)bi * 16384 + ((kc * 128 + nrow) << 3)] = o;
    }
}

// ---------------- CSR build via bucket counting sort ----------------

__global__ __launch_bounds__(256) void bucket_hist_kernel(const int* __restrict__ rows,
                                                          int* __restrict__ bhist, int E)
{
    __shared__ int h[512];
    int t = threadIdx.x;
    h[t] = 0; h[t + 256] = 0;
    __syncthreads();
    int base = blockIdx.x * 4096;
#pragma unroll
    for (int i = 0; i < 16; ++i) {
        int e = base + i * 256 + t;
        if (e < E) atomicAdd(&h[rows[e] >> BSH], 1);
    }
    __syncthreads();
    if (h[t]) atomicAdd(&bhist[t], h[t]);
    if (h[t + 256]) atomicAdd(&bhist[t + 256], h[t + 256]);
}

__global__ __launch_bounds__(256) void bucket_scan_kernel(const int* __restrict__ bhist,
                                                          int* __restrict__ boff, int* __restrict__ bcur,
                                                          int* __restrict__ row_ptr, int NB, int N, int E)
{
    __shared__ int h[512], sx[512], wt[4];
    int t = threadIdx.x;
    h[t] = bhist[t]; h[t + 256] = bhist[t + 256];
    __syncthreads();
    int v0 = h[2 * t], v1 = h[2 * t + 1];
    int s = v0 + v1, incl = s;
    for (int o = 1; o < 64; o <<= 1) { int u = __shfl_up(incl, o); if ((t & 63) >= o) incl += u; }
    if ((t & 63) == 63) wt[t >> 6] = incl;
    __syncthreads();
    int woff = 0, w = t >> 6;
    for (int i = 0; i < w; ++i) woff += wt[i];
    int excl = woff + incl - s;
    sx[2 * t] = excl; sx[2 * t + 1] = excl + v0;
    __syncthreads();
    if (t < NB)       { boff[t] = sx[t];       bcur[t] = sx[t]; }
    if (t + 256 < NB) { boff[t + 256] = sx[t + 256]; bcur[t + 256] = sx[t + 256]; }
    if (t == 0) { boff[NB] = E; row_ptr[N] = E; }
}

// counting-sort a 4096-edge chunk by bucket in LDS; flush contiguous runs.
// bcv.x packs col | (row&511)<<COLBITS
__global__ __launch_bounds__(256) void bucket_bin_kernel(
    const int* __restrict__ rows, const int* __restrict__ cols, const float* __restrict__ val,
    int* __restrict__ bcur, int2* __restrict__ bcv, int E)
{
    __shared__ int hist[512], sx[512], cnt[512], gbase[512], wt[4];
    __shared__ int mb[4096];
    __shared__ int2 mcv[4096];
    int t = threadIdx.x;
    hist[t] = 0; hist[t + 256] = 0; cnt[t] = 0; cnt[t + 256] = 0;
    __syncthreads();
    int base = blockIdx.x * 4096;
    int r[16];
#pragma unroll
    for (int i = 0; i < 16; ++i) {
        int e = base + i * 256 + t;
        r[i] = (e < E) ? rows[e] : -1;
        if (r[i] >= 0) atomicAdd(&hist[r[i] >> BSH], 1);
    }
    __syncthreads();
    int v0 = hist[2 * t], v1 = hist[2 * t + 1];
    int s = v0 + v1, incl = s;
    for (int o = 1; o < 64; o <<= 1) { int u = __shfl_up(incl, o); if ((t & 63) >= o) incl += u; }
    if ((t & 63) == 63) wt[t >> 6] = incl;
    __syncthreads();
    int woff = 0, w = t >> 6;
    for (int i = 0; i < w; ++i) woff += wt[i];
    int excl = woff + incl - s;
    sx[2 * t] = excl; sx[2 * t + 1] = excl + v0;
    __syncthreads();
    for (int bb = t; bb < 512; bb += 256)
        if (hist[bb]) gbase[bb] = atomicAdd(&bcur[bb], hist[bb]);
    __syncthreads();
#pragma unroll
    for (int i = 0; i < 16; ++i) {
        if (r[i] < 0) continue;
        int e = base + i * 256 + t;
        int bb = r[i] >> BSH;
        int p = atomicAdd(&cnt[bb], 1);
        int loc = sx[bb] + p;
        mb[loc] = bb;
        int2 cv;
        cv.x = cols[e] | ((r[i] & (BROWS - 1)) << COLBITS);
        cv.y = __float_as_int(val[e]);
        mcv[loc] = cv;
    }
    __syncthreads();
    int Mv = sx[511] + hist[511];
    for (int loc = t; loc < Mv; loc += 256) {
        int bb = mb[loc];
        int gidx = gbase[bb] + (loc - sx[bb]);
        bcv[gidx] = mcv[loc];
    }
}

// one block per bucket: row-hist -> row_ptr; place edges into exact CSR slots (col stripped)
__global__ __launch_bounds__(256) void bucket_place_kernel(
    const int2* __restrict__ bcv, const int* __restrict__ boff, int* __restrict__ row_ptr,
    int2* __restrict__ cpack, int N)
{
    __shared__ int rcnt[512], sx[512], wt[4];
    int b = blockIdx.x;
    int t = threadIdx.x;
    rcnt[t] = 0; rcnt[t + 256] = 0;
    __syncthreads();
    int rbase = b << BSH;
    int rn = min(BROWS, N - rbase);
    int lo = boff[b], hi = boff[b + 1];
    for (int p = lo + t; p < hi; p += 256)
        atomicAdd(&rcnt[((unsigned)bcv[p].x) >> COLBITS], 1);
    __syncthreads();
    int v0 = rcnt[2 * t], v1 = rcnt[2 * t + 1];
    int s = v0 + v1, incl = s;
    for (int o = 1; o < 64; o <<= 1) { int u = __shfl_up(incl, o); if ((t & 63) >= o) incl += u; }
    if ((t & 63) == 63) wt[t >> 6] = incl;
    __syncthreads();
    int woff = 0, w = t >> 6;
    for (int i = 0; i < w; ++i) woff += wt[i];
    int excl = woff + incl - s;
    sx[2 * t] = excl; sx[2 * t + 1] = excl + v0;
    __syncthreads();
    if (t < rn)       row_ptr[rbase + t] = lo + sx[t];
    if (t + 256 < rn) row_ptr[rbase + t + 256] = lo + sx[t + 256];
    __syncthreads();
    sx[t] += lo; sx[t + 256] += lo;
    __syncthreads();
    for (int p = lo + t; p < hi; p += 256) {
        int2 cv = bcv[p];
        int rin = ((unsigned)cv.x) >> COLBITS;
        int slot = atomicAdd(&sx[rin], 1);
        cv.x &= (1 << COLBITS) - 1;
        cpack[slot] = cv;
    }
}

// ---------------- MFMA GEMM: Y[M x Nout] = X[M x 128] @ W[Nout x 128]^T (+bias)(+elu) ----
// Wf is fragment-packed (see prep). X staged in LDS with XOR chunk swizzle:
// chunk (r, kc) at elem offset (r*16 + (kc ^ (r&15)))*8  -> conflict-free reads & writes.

template<int IN_BF16, int OUT_BF16, int ACT>
__global__ __launch_bounds__(256, 4) void gemm_mfma(
    const void* __restrict__ Xv, const bf16* __restrict__ Wf,
    const float* __restrict__ bias, void* __restrict__ Yv, int M, int Nout)
{
    __shared__ bf16 Xs[128 * 128];
    const int tid = threadIdx.x;
    const int rb = blockIdx.x * 128;
    const int cb = blockIdx.y * 128;
    const bf16* Wfb = Wf + (size_t)cb * CCH;

    if (IN_BF16) {
#pragma unroll
        for (int i = 0; i < 8; ++i) {
            int c = tid + i * 256;
            int r = c >> 4, kc = c & 15;
            int grow = rb + r;
            bf16x8 o = {};
            if (grow < M) o = *(const bf16x8*)&((const bf16*)Xv)[(size_t)grow * CCH + kc * 8];
            *(bf16x8*)&Xs[(r * 16 + (kc ^ (r & 15))) << 3] = o;
        }
    } else {
#pragma unroll
        for (int i = 0; i < 16; ++i) {
            int c = tid + i * 256;
            int r = c >> 5, sub = c & 31;
            int kc = sub >> 1, half = sub & 1;
            int grow = rb + r;
            bf16x4 o = {};
            if (grow < M) {
                float4 xv = *(const float4*)&((const float*)Xv)[(size_t)grow * CCH + kc * 8 + half * 4];
                o[0] = (bf16)xv.x; o[1] = (bf16)xv.y; o[2] = (bf16)xv.z; o[3] = (bf16)xv.w;
            }
            *(bf16x4*)&Xs[((r * 16 + (kc ^ (r & 15))) << 3) + half * 4] = o;
        }
    }
    __syncthreads();

    const int w = tid >> 6, lane = tid & 63;
    const int col16 = lane & 15, quad = lane >> 4;
    const int wm = (w & 1) * 64, wn = (w >> 1) * 64;

    f32x4 acc[4][4] = {};
#pragma unroll
    for (int kk = 0; kk < 4; ++kk) {
        const int kc = kk * 4 + quad;
        bf16x8 bfr[4], af[4];
#pragma unroll
        for (int ni = 0; ni < 4; ++ni)
            bfr[ni] = *(const bf16x8*)&Wfb[(size_t)((kc * 128 + wn + ni * 16 + col16) << 3)];
#pragma unroll
        for (int mi = 0; mi < 4; ++mi) {
            int r = wm + mi * 16 + col16;
            af[mi] = *(const bf16x8*)&Xs[(r * 16 + (kc ^ col16)) << 3];
        }
#pragma unroll
        for (int mi = 0; mi < 4; ++mi)
#pragma unroll
            for (int ni = 0; ni < 4; ++ni)
                acc[mi][ni] = __builtin_amdgcn_mfma_f32_16x16x32_bf16(af[mi], bfr[ni], acc[mi][ni], 0, 0, 0);
    }

#pragma unroll
    for (int mi = 0; mi < 4; ++mi) {
#pragma unroll
        for (int r = 0; r < 4; ++r) {
            int row = rb + wm + mi * 16 + quad * 4 + r;
            if (row >= M) continue;
#pragma unroll
            for (int ni = 0; ni < 4; ++ni) {
                int col = cb + wn + ni * 16 + col16;
                float vv = acc[mi][ni][r];
                if (bias) vv += bias[col];
                if (ACT == 1) vv = vv > 0.f ? vv : expm1f(vv);   // elu
                if (OUT_BF16) ((bf16*)Yv)[(size_t)row * Nout + col] = (bf16)vv;
                else          ((float*)Yv)[(size_t)row * Nout + col] = vv;
            }
        }
    }
}

// ---------------- fused dual-GEMM + GRU (+bn, + tt/scores or mol out) ----------------
// 64-row tile, block 256 = 4 waves, wave w covers cols [w*32, w*32+32).
// gi = Agi @ Wih^T + bih ; gh = mean @ Whh^T + bhh ; phases cb0->r, cb2->n, cb1->z,h.
// TT: out bf16 + scores (next stage); else out fp32 (mol).
template<int TT>
__global__ __launch_bounds__(256, 2) void gru_gemm_kernel(
    const bf16* __restrict__ Agi, const float* __restrict__ meanf,
    const bf16* __restrict__ Wih, const bf16* __restrict__ Whh,
    const float* __restrict__ bih, const float* __restrict__ bhh,
    const float* __restrict__ sc4, const float* __restrict__ sh4,
    void* __restrict__ out,
    const float* __restrict__ vsp2, const float* __restrict__ c02, float* __restrict__ scores,
    int M)
{
    __shared__ bf16 Xi[64 * 128];
    __shared__ bf16 Xh[64 * 128];
    __shared__ float sred[64];
    const int tid = threadIdx.x;
    const int rb = blockIdx.x * 64;

    if (TT && tid < 64) sred[tid] = 0.f;
    // stage Agi (bf16): 64 rows x 16 chunks
#pragma unroll
    for (int i = 0; i < 4; ++i) {
        int c = tid + i * 256;
        int r = c >> 4, kc = c & 15;
        int grow = rb + r;
        bf16x8 o = {};
        if (grow < M) o = *(const bf16x8*)&Agi[(size_t)grow * CCH + kc * 8];
        *(bf16x8*)&Xi[(r * 16 + (kc ^ (r & 15))) << 3] = o;
    }
    // stage mean (fp32 -> bf16)
#pragma unroll
    for (int i = 0; i < 8; ++i) {
        int c = tid + i * 256;
        int r = c >> 5, sub = c & 31;
        int kc = sub >> 1, half = sub & 1;
        int grow = rb + r;
        bf16x4 o = {};
        if (grow < M) {
            float4 xv = *(const float4*)&meanf[(size_t)grow * CCH + kc * 8 + half * 4];
            o[0] = (bf16)xv.x; o[1] = (bf16)xv.y; o[2] = (bf16)xv.z; o[3] = (bf16)xv.w;
        }
        *(bf16x4*)&Xh[((r * 16 + (kc ^ (r & 15))) << 3) + half * 4] = o;
    }
    __syncthreads();

    const int w = tid >> 6, lane = tid & 63;
    const int col16 = lane & 15, quad = lane >> 4;

    f32x4 carry[4][2];   // r, then n

    const int phase_cb[3] = {0, 2, 1};
#pragma unroll
    for (int ph = 0; ph < 3; ++ph) {
        const int cb = phase_cb[ph];
        const bf16* Wi_t = Wih + (size_t)cb * 16384;
        const bf16* Wh_t = Whh + (size_t)cb * 16384;
        f32x4 ai[4][2] = {};
        f32x4 ah[4][2] = {};
#pragma unroll
        for (int kk = 0; kk < 4; ++kk) {
            const int kc = kk * 4 + quad;
            bf16x8 bi_f[2], bh_f[2], xi_f[4], xh_f[4];
#pragma unroll
            for (int ni = 0; ni < 2; ++ni) {
                int wc = w * 32 + ni * 16 + col16;
                bi_f[ni] = *(const bf16x8*)&Wi_t[(size_t)((kc * 128 + wc) << 3)];
                bh_f[ni] = *(const bf16x8*)&Wh_t[(size_t)((kc * 128 + wc) << 3)];
            }
#pragma unroll
            for (int mi = 0; mi < 4; ++mi) {
                int r = mi * 16 + col16;
                xi_f[mi] = *(const bf16x8*)&Xi[(r * 16 + (kc ^ col16)) << 3];
                xh_f[mi] = *(const bf16x8*)&Xh[(r * 16 + (kc ^ col16)) << 3];
            }
#pragma unroll
            for (int mi = 0; mi < 4; ++mi)
#pragma unroll
                for (int ni = 0; ni < 2; ++ni) {
                    ai[mi][ni] = __builtin_amdgcn_mfma_f32_16x16x32_bf16(xi_f[mi], bi_f[ni], ai[mi][ni], 0, 0, 0);
                    ah[mi][ni] = __builtin_amdgcn_mfma_f32_16x16x32_bf16(xh_f[mi], bh_f[ni], ah[mi][ni], 0, 0, 0);
                }
        }
        // combine
        const int gofs = cb * 128;
#pragma unroll
        for (int mi = 0; mi < 4; ++mi) {
#pragma unroll
            for (int ni = 0; ni < 2; ++ni) {
                int col = w * 32 + ni * 16 + col16;
                float bi_v = bih[gofs + col], bh_v = bhh[gofs + col];
#pragma unroll
                for (int rr = 0; rr < 4; ++rr) {
                    float vi = ai[mi][ni][rr] + bi_v;
                    float vh = ah[mi][ni][rr] + bh_v;
                    if (ph == 0) {                       // r = sigmoid(ir+hr)
                        carry[mi][ni][rr] = 1.f / (1.f + __expf(-(vi + vh)));
                    } else if (ph == 1) {                // n = tanh(inn + r*hn)
                        carry[mi][ni][rr] = tanhf(vi + carry[mi][ni][rr] * vh);
                    } else {                             // z; h; epilogue
                        float z = 1.f / (1.f + __expf(-(vi + vh)));
                        int row = rb + mi * 16 + quad * 4 + rr;
                        float mval = (row < M) ? meanf[(size_t)row * CCH + col] : 0.f;
                        float h = (1.f - z) * carry[mi][ni][rr] + z * mval;
                        h = fmaxf(h, 0.f);
                        float o = h * sc4[col] + sh4[col];
                        carry[mi][ni][rr] = o;           // reuse as output holder
                    }
                }
            }
        }
    }

    // stores + optional scores
#pragma unroll
    for (int mi = 0; mi < 4; ++mi) {
#pragma unroll
        for (int rr = 0; rr < 4; ++rr) {
            int rloc = mi * 16 + quad * 4 + rr;
            int row = rb + rloc;
            float p = 0.f;
#pragma unroll
            for (int ni = 0; ni < 2; ++ni) {
                int col = w * 32 + ni * 16 + col16;
                float o = carry[mi][ni][rr];
                if (row < M) {
                    if (TT) ((bf16*)out)[(size_t)row * CCH + col] = (bf16)o;
                    else    ((float*)out)[(size_t)row * CCH + col] = o;
                }
                if (TT) p += o * vsp2[col];
            }
            if (TT && row < M) atomicAdd(&sred[rloc], p);
        }
    }
    if (TT) {
        __syncthreads();
        if (tid < 64 && rb + tid < M) scores[rb + tid] = sred[tid] + c02[0];
    }
}

// ---------------- SpMM (CSR gather): 16 lanes/row x bf16x8, 8-edge unroll ----------------
template<int SCORES>
__global__ __launch_bounds__(256) void spmm_csr_kernel(
    const int* __restrict__ row_ptr, const int2* __restrict__ cpack,
    const bf16* __restrict__ Xin, bf16* __restrict__ Y,
    const float* __restrict__ bvec, const float* __restrict__ sc, const float* __restrict__ sh,
    const float* __restrict__ vsp, const float* __restrict__ c0p, float* __restrict__ scores,
    int Nrow)
{
    int gid = blockIdx.x * 256 + threadIdx.x;
    int row = gid >> 4;
    if (row >= Nrow) return;
    int l8 = (gid & 15) << 3;
    int st = row_ptr[row], en = row_ptr[row + 1];
    float acc[8] = {};
    int j = st;
    for (; j + 8 <= en; j += 8) {
        int2 p[8]; bf16x8 x[8];
#pragma unroll
        for (int u = 0; u < 8; ++u) p[u] = cpack[j + u];
#pragma unroll
        for (int u = 0; u < 8; ++u) x[u] = *(const bf16x8*)&Xin[(size_t)p[u].x * CCH + l8];
#pragma unroll
        for (int u = 0; u < 8; ++u) {
            float vv = __int_as_float(p[u].y);
#pragma unroll
            for (int q = 0; q < 8; ++q) acc[q] += vv * (float)x[u][q];
        }
    }
    if (j + 4 <= en) {
        int2 p[4]; bf16x8 x[4];
#pragma unroll
        for (int u = 0; u < 4; ++u) p[u] = cpack[j + u];
#pragma unroll
        for (int u = 0; u < 4; ++u) x[u] = *(const bf16x8*)&Xin[(size_t)p[u].x * CCH + l8];
#pragma unroll
        for (int u = 0; u < 4; ++u) {
            float vv = __int_as_float(p[u].y);
#pragma unroll
            for (int q = 0; q < 8; ++q) acc[q] += vv * (float)x[u][q];
        }
        j += 4;
    }
    if (j + 2 <= en) {
        int2 p0 = cpack[j], p1 = cpack[j + 1];
        bf16x8 x0 = *(const bf16x8*)&Xin[(size_t)p0.x * CCH + l8];
        bf16x8 x1 = *(const bf16x8*)&Xin[(size_t)p1.x * CCH + l8];
        float v0 = __int_as_float(p0.y), v1 = __int_as_float(p1.y);
#pragma unroll
        for (int q = 0; q < 8; ++q) acc[q] += v0 * (float)x0[q] + v1 * (float)x1[q];
        j += 2;
    }
    if (j < en) {
        int2 p0 = cpack[j];
        bf16x8 x0 = *(const bf16x8*)&Xin[(size_t)p0.x * CCH + l8];
        float v0 = __int_as_float(p0.y);
#pragma unroll
        for (int q = 0; q < 8; ++q) acc[q] += v0 * (float)x0[q];
    }
    float o[8];
    bf16x8 ov;
#pragma unroll
    for (int q = 0; q < 8; ++q) {
        o[q] = fmaxf((acc[q] + bvec[l8 + q]) * sc[l8 + q] + sh[l8 + q], 0.f);
        ov[q] = (bf16)o[q];
    }
    *(bf16x8*)&Y[(size_t)row * CCH + l8] = ov;
    if (SCORES) {
        float p = 0.f;
#pragma unroll
        for (int q = 0; q < 8; ++q) p += o[q] * vsp[l8 + q];
        for (int d = 8; d; d >>= 1) p += __shfl_down(p, d, 16);
        if ((gid & 15) == 0) scores[row] = p + c0p[0];
    }
}

// ---------------- fused pool + attention pool (per segment) ----------------
__global__ __launch_bounds__(128) void segstage_kernel(
    const bf16* __restrict__ X, const float* __restrict__ sarr, const int* __restrict__ starts,
    const float* __restrict__ sc2, const float* __restrict__ sh2,
    const float* __restrict__ sc3, const float* __restrict__ sh3,
    const float* __restrict__ vd, float* __restrict__ mean, bf16* __restrict__ upool)
{
    __shared__ float red[2];
    __shared__ float adsh;
    int t = blockIdx.x;
    int c = threadIdx.x;
    int st = starts[t], en = starts[t + 1];
    float sum = 0.f;
    for (int i = st; i < en; ++i) sum += (float)X[(size_t)i * CCH + c];
    float cnt = (float)(en - st);
    float poolb = fmaxf(sum * sc2[c] + cnt * sh2[c], 0.f);
    float mv = poolb * sc3[c] + sh3[c];
    mean[(size_t)t * CCH + c] = mv;
    float p = mv * vd[c];
    for (int o = 32; o; o >>= 1) p += __shfl_down(p, o);
    if ((c & 63) == 0) red[c >> 6] = p;
    __syncthreads();
    if (c == 0) adsh = red[0] + red[1];
    __syncthreads();
    if (en == st) { upool[(size_t)t * CCH + c] = (bf16)0.f; return; }
    float adt = adsh;
    float lm = -3.0e38f;
    for (int i = st + c; i < en; i += 128) {
        float a = sarr[i] + adt;
        a = a > 0.f ? a : 0.01f * a;
        lm = fmaxf(lm, a);
    }
    for (int o = 32; o; o >>= 1) lm = fmaxf(lm, __shfl_down(lm, o));
    if ((c & 63) == 0) red[c >> 6] = lm;
    __syncthreads();
    float m = fmaxf(red[0], red[1]);
    float u = 0.f, den = 0.f;
    for (int i = st; i < en; ++i) {
        float a = sarr[i] + adt;
        a = a > 0.f ? a : 0.01f * a;
        float e = __expf(a - m);
        den += e;
        u += e * (float)X[(size_t)i * CCH + c];
    }
    upool[(size_t)t * CCH + c] = (bf16)((u / den) * sc2[c] + sh2[c]);
}

// predictor: one block (64 thr) per molecule
__global__ __launch_bounds__(64) void pred_kernel(
    const float* __restrict__ mol, const float* __restrict__ pW1, const float* __restrict__ pb1,
    const float* __restrict__ pW2, const float* __restrict__ pb2, float* __restrict__ out)
{
    __shared__ float row[CCH];
    int m = blockIdx.x;
    int j = threadIdx.x;
    row[j] = mol[(size_t)m * CCH + j];
    row[j + 64] = mol[(size_t)m * CCH + 64 + j];
    __syncthreads();
    float h = pb1[j];
#pragma unroll
    for (int k = 0; k < CCH; ++k) h += row[k] * pW1[j * CCH + k];
    h = fmaxf(h, 0.f);
    float p = h * pW2[j];
    for (int o = 32; o; o >>= 1) p += __shfl_down(p, o);
    if (j == 0) out[m] = p + pb2[0];
}

// ---------------- host ----------------

extern "C" void kernel_launch(void* const* d_in, const int* in_sizes, int n_in,
                              void* d_out, int out_size, void* d_ws, size_t ws_size,
                              hipStream_t stream)
{
    (void)n_in; (void)ws_size;
    const float* node_attr      = (const float*)d_in[0];
    const int*   adj_index      = (const int*)  d_in[1];
    const float* adj_value      = (const float*)d_in[2];
    const int*   tt_node_batch  = (const int*)  d_in[3];
    const int*   tt_graph_batch = (const int*)  d_in[4];
    const float* W_gcn    = (const float*)d_in[5];
    const float* b_gcn    = (const float*)d_in[6];
    const float* bn_gamma = (const float*)d_in[7];
    const float* bn_beta  = (const float*)d_in[8];
    const float* bn_mean  = (const float*)d_in[9];
    const float* bn_var   = (const float*)d_in[10];
    const float* gat_Wsrc = (const float*)d_in[11];
    const float* gat_Wdst = (const float*)d_in[12];
    const float* gat_asrc = (const float*)d_in[13];
    const float* gat_adst = (const float*)d_in[14];
    const float* gat_bias = (const float*)d_in[15];
    const float* gru_Wih  = (const float*)d_in[16];
    const float* gru_Whh  = (const float*)d_in[17];
    const float* gru_bih  = (const float*)d_in[18];
    const float* gru_bhh  = (const float*)d_in[19];
    const float* pW1 = (const float*)d_in[20];
    const float* pb1 = (const float*)d_in[21];
    const float* pW2 = (const float*)d_in[22];
    const float* pb2 = (const float*)d_in[23];

    const int E    = in_sizes[2];
    const int N    = in_sizes[3];
    const int NTT  = in_sizes[4];
    const int NMOL = out_size;
    const int NB   = (N + BROWS - 1) >> BSH;

    const int* adj_rows = adj_index;
    const int* adj_cols = adj_index + E;

    // ---- workspace carve ----
    char* wsb = (char*)d_ws;
    size_t off = 0;
    auto carve = [&](size_t bytes) -> char* {
        char* p = wsb + off;
        off = (off + bytes + 255) & ~(size_t)255;
        return p;
    };
    bf16* bufB = (bf16*)carve((size_t)N * CCH * 2);
    bf16* bufA = (bf16*)carve((size_t)N * CCH * 2);
    bf16* tt   = (bf16*)carve((size_t)NTT * CCH * 2);
    float* mol  = (float*)carve((size_t)NMOL * CCH * 4);
    float* mean  = (float*)carve((size_t)NTT * CCH * 4);
    bf16*  upool = (bf16*)carve((size_t)NTT * CCH * 2);
    bf16*  gbuf  = (bf16*)carve((size_t)NTT * CCH * 2);
    float* scores = (float*)carve((size_t)N * 4);
    int* starts_tt  = (int*)carve((size_t)(NTT + 1) * 4);
    int* starts_mol = (int*)carve((size_t)(NMOL + 1) * 4);
    float* bnsc = (float*)carve(8 * CCH * 4);
    float* bnsh = (float*)carve(8 * CCH * 4);
    float* vsp  = (float*)carve(2 * CCH * 4);
    float* vd   = (float*)carve(2 * CCH * 4);
    float* c0   = (float*)carve(2 * 4);
    bf16* Wgcnb = (bf16*)carve((size_t)2 * CCH * CCH * 2);
    bf16* Wsrcb = (bf16*)carve((size_t)2 * CCH * CCH * 2);
    bf16* Wihb  = (bf16*)carve((size_t)2 * G3 * CCH * 2);
    bf16* Whhb  = (bf16*)carve((size_t)2 * G3 * CCH * 2);
    int*   bhist   = (int*)carve(512 * 4);
    int*   boff    = (int*)carve((size_t)(NB + 1) * 4);
    int*   bcur    = (int*)carve((size_t)NB * 4);
    int*   row_ptr = (int*)carve((size_t)(N + 1) * 4);
    int2*  bcv     = (int2*)carve((size_t)E * 8);
    int2*  cpack   = (int2*)carve((size_t)E * 8);

    // ---- fused prep ----
    const int B1 = 4;
    const int B2 = B1 + 2;
    const int B3 = B2 + (NTT + 1 + 255) / 256;
    const int B4 = B3 + (NMOL + 1 + 255) / 256;
    const int B5 = B4 + 1;
    const int B6 = B5 + 16;
    const int B7 = B6 + 16;
    const int B8 = B7 + 48;
    const int B9 = B8 + 48;
    prep_kernel<<<B9, 256, 0, stream>>>(
        bn_gamma, bn_beta, bn_mean, bn_var, bnsc, bnsh,
        gat_Wsrc, gat_Wdst, gat_asrc, gat_adst, vsp, vd, c0,
        tt_node_batch, N, NTT, starts_tt,
        tt_graph_batch, NMOL, starts_mol,
        bhist,
        W_gcn, Wgcnb, Wsrcb, gru_Wih, Wihb, gru_Whh, Whhb,
        B1, B2, B3, B4, B5, B6, B7, B8);

    // ---- CSR build ----
    const int nchunk = (E + 4095) / 4096;
    bucket_hist_kernel<<<nchunk, 256, 0, stream>>>(adj_rows, bhist, E);
    bucket_scan_kernel<<<1, 256, 0, stream>>>(bhist, boff, bcur, row_ptr, NB, N, E);
    bucket_bin_kernel<<<nchunk, 256, 0, stream>>>(adj_rows, adj_cols, adj_value, bcur, bcv, E);
    bucket_place_kernel<<<NB, 256, 0, stream>>>(bcv, boff, row_ptr, cpack, N);

    // ---- GCN x2 ----
    dim3 gg((N + 127) / 128, 1);
    const int spmm_blocks = ((size_t)N * 16 + 255) / 256;
    gemm_mfma<0, 1, 0><<<gg, 256, 0, stream>>>(node_attr, Wgcnb, nullptr, bufB, N, CCH);
    spmm_csr_kernel<0><<<spmm_blocks, 256, 0, stream>>>(
        row_ptr, cpack, bufB, bufA, b_gcn, bnsc, bnsh, nullptr, nullptr, nullptr, N);
    gemm_mfma<1, 1, 0><<<gg, 256, 0, stream>>>(bufA, Wgcnb + CCH * CCH, nullptr, bufB, N, CCH);
    spmm_csr_kernel<1><<<spmm_blocks, 256, 0, stream>>>(
        row_ptr, cpack, bufB, bufA, b_gcn + CCH, bnsc + CCH, bnsh + CCH,
        vsp, c0, scores, N);

    // ---- tt stage: N -> NTT (fused GRU-GEMM, bf16 out + mol-stage scores) ----
    {
        const int bnb = 2, gi = 0, nseg = NTT;
        segstage_kernel<<<nseg, 128, 0, stream>>>(bufA, scores, starts_tt,
            bnsc + bnb * CCH, bnsh + bnb * CCH, bnsc + (bnb + 1) * CCH, bnsh + (bnb + 1) * CCH,
            vd + gi * CCH, mean, upool);
        dim3 g1((nseg + 127) / 128, 1);
        gemm_mfma<1, 1, 1><<<g1, 256, 0, stream>>>(upool, Wsrcb + gi * CCH * CCH,
                                                   gat_bias + gi * CCH, gbuf, nseg, CCH);
        gru_gemm_kernel<1><<<(nseg + 63) / 64, 256, 0, stream>>>(
            gbuf, mean, Wihb + gi * G3 * CCH, Whhb + gi * G3 * CCH,
            gru_bih + gi * G3, gru_bhh + gi * G3,
            bnsc + (bnb + 2) * CCH, bnsh + (bnb + 2) * CCH,
            tt, vsp + CCH, c0 + 1, scores, nseg);
    }

    // ---- mol stage: NTT -> NMOL (fused GRU-GEMM, fp32 out) + predictor ----
    {
        const int bnb = 5, gi = 1, nseg = NMOL;
        segstage_kernel<<<nseg, 128, 0, stream>>>(tt, scores, starts_mol,
            bnsc + bnb * CCH, bnsh + bnb * CCH, bnsc + (bnb + 1) * CCH, bnsh + (bnb + 1) * CCH,
            vd + gi * CCH, mean, upool);
        dim3 g1((nseg + 127) / 128, 1);
        gemm_mfma<1, 1, 1><<<g1, 256, 0, stream>>>(upool, Wsrcb + gi * CCH * CCH,
                                                   gat_bias + gi * CCH, gbuf, nseg, CCH);
        gru_gemm_kernel<0><<<(nseg + 63) / 64, 256, 0, stream>>>(
            gbuf, mean, Wihb + gi * G3 * CCH, Whhb + gi * G3 * CCH,
            gru_bih + gi * G3, gru_bhh + gi * G3,
            bnsc + (bnb + 2) * CCH, bnsh + (bnb + 2) * CCH,
            mol, nullptr, nullptr, nullptr, nseg);
        pred_kernel<<<NMOL, 64, 0, stream>>>(mol, pW1, pb1, pW2, pb2, (float*)d_out);
    }
}

// Round 9
// 586.155 us; speedup vs baseline: 1.0558x; 1.0558x over previous
//
#include <hip/hip_runtime.h>
#include <math.h>

#define CCH 128
#define G3  384
#define BN_EPS 1e-5f
#define BSH 9              // bucket shift: 512 rows/bucket
#define BROWS 512
#define COLBITS 19         // col < 2^19 (N=200000); row-in-bucket packed above

typedef __bf16 bf16;
typedef __bf16 bf16x2 __attribute__((ext_vector_type(2)));
typedef __bf16 bf16x4 __attribute__((ext_vector_type(4)));
typedef __bf16 bf16x8 __attribute__((ext_vector_type(8)));
typedef float f32x4 __attribute__((ext_vector_type(4)));

// ---------------- fused prep kernel (block-range roles) ----------------
__global__ __launch_bounds__(256) void prep_kernel(
    const float* __restrict__ g, const float* __restrict__ b,
    const float* __restrict__ m, const float* __restrict__ v,
    float* __restrict__ bnsc, float* __restrict__ bnsh,
    const float* __restrict__ Wsrc, const float* __restrict__ Wdst,
    const float* __restrict__ asrc, const float* __restrict__ adst,
    float* __restrict__ vsp, float* __restrict__ vd, float* __restrict__ c0,
    const int* __restrict__ tt_node_batch, int N, int NTT, int* __restrict__ starts_tt,
    const int* __restrict__ tt_graph_batch, int NMOL, int* __restrict__ starts_mol,
    int* __restrict__ bhist,
    const float* __restrict__ Wgcn, bf16* __restrict__ Wgcnb,
    bf16* __restrict__ Wsrcb,
    const float* __restrict__ Wih, bf16* __restrict__ Wihb,
    const float* __restrict__ Whh, bf16* __restrict__ Whhb,
    int B1, int B2, int B3, int B4, int B5, int B6, int B7, int B8)
{
    __shared__ float red[2];
    const int bid = blockIdx.x;
    const int tid = threadIdx.x;
    if (bid < B1) {
        int idx = bid * 256 + tid;
        if (idx < 8 * CCH) {
            float s = g[idx] / sqrtf(v[idx] + BN_EPS);
            bnsc[idx] = s;
            bnsh[idx] = b[idx] - m[idx] * s;
        }
    } else if (bid < B2) {
        int s = bid - B1;
        int which = tid >> 7, k = tid & 127;
        const float* W = (which ? Wdst : Wsrc) + s * CCH * CCH;
        const float* a = (which ? adst : asrc) + s * CCH;
        float acc = 0.f;
        for (int j = 0; j < CCH; ++j) acc += W[j * CCH + k] * a[j];
        if (which) {
            vd[s * CCH + k] = acc;
        } else {
            int l = 2 + 3 * s;
            float scl = g[l * CCH + k] / sqrtf(v[l * CCH + k] + BN_EPS);
            float shf = b[l * CCH + k] - m[l * CCH + k] * scl;
            vsp[s * CCH + k] = acc * scl;
            float p = shf * acc;
            for (int o = 32; o; o >>= 1) p += __shfl_down(p, o);
            if ((k & 63) == 0) red[k >> 6] = p;
        }
        __syncthreads();
        if (tid == 0) c0[s] = red[0] + red[1];
    } else if (bid < B3) {
        int s = (bid - B2) * 256 + tid;
        if (s <= NTT) {
            int lo = 0, hi = N;
            while (lo < hi) { int mid = (lo + hi) >> 1; if (tt_node_batch[mid] < s) lo = mid + 1; else hi = mid; }
            starts_tt[s] = lo;
        }
    } else if (bid < B4) {
        int s = (bid - B3) * 256 + tid;
        if (s <= NMOL) {
            int lo = 0, hi = NTT;
            while (lo < hi) { int mid = (lo + hi) >> 1; if (tt_graph_batch[mid] < s) lo = mid + 1; else hi = mid; }
            starts_mol[s] = lo;
        }
    } else if (bid < B5) {
        bhist[tid] = 0; bhist[tid + 256] = 0;
    } else {
        const float* src; bf16* dst; int u0;
        if (bid < B6)      { src = Wgcn; dst = Wgcnb; u0 = (bid - B5) * 256; }
        else if (bid < B7) { src = Wsrc; dst = Wsrcb; u0 = (bid - B6) * 256; }
        else if (bid < B8) { src = Wih;  dst = Wihb;  u0 = (bid - B7) * 256; }
        else               { src = Whh;  dst = Whhb;  u0 = (bid - B8) * 256; }
        int u = u0 + tid;
        int row = u >> 4, kc = u & 15;
        int bi = row >> 7, nrow = row & 127;
        const float* s = src + (size_t)row * CCH + kc * 8;
        float4 a = *(const float4*)s;
        float4 b4 = *(const float4*)(s + 4);
        bf16x8 o = { (bf16)a.x, (bf16)a.y, (bf16)a.z, (bf16)a.w,
                     (bf16)b4.x, (bf16)b4.y, (bf16)b4.z, (bf16)b4.w };
        *(bf16x8*)&dst[(size_t)bi * 16384 + ((kc * 128 + nrow) << 3)] = o;
    }
}

// ---------------- CSR build via bucket counting sort ----------------

__global__ __launch_bounds__(256) void bucket_hist_kernel(const int* __restrict__ rows,
                                                          int* __restrict__ bhist, int E)
{
    __shared__ int h[512];
    int t = threadIdx.x;
    h[t] = 0; h[t + 256] = 0;
    __syncthreads();
    int base = blockIdx.x * 4096;
#pragma unroll
    for (int i = 0; i < 16; ++i) {
        int e = base + i * 256 + t;
        if (e < E) atomicAdd(&h[rows[e] >> BSH], 1);
    }
    __syncthreads();
    if (h[t]) atomicAdd(&bhist[t], h[t]);
    if (h[t + 256]) atomicAdd(&bhist[t + 256], h[t + 256]);
}

__global__ __launch_bounds__(256) void bucket_scan_kernel(const int* __restrict__ bhist,
                                                          int* __restrict__ boff, int* __restrict__ bcur,
                                                          int* __restrict__ row_ptr, int NB, int N, int E)
{
    __shared__ int h[512], sx[512], wt[4];
    int t = threadIdx.x;
    h[t] = bhist[t]; h[t + 256] = bhist[t + 256];
    __syncthreads();
    int v0 = h[2 * t], v1 = h[2 * t + 1];
    int s = v0 + v1, incl = s;
    for (int o = 1; o < 64; o <<= 1) { int u = __shfl_up(incl, o); if ((t & 63) >= o) incl += u; }
    if ((t & 63) == 63) wt[t >> 6] = incl;
    __syncthreads();
    int woff = 0, w = t >> 6;
    for (int i = 0; i < w; ++i) woff += wt[i];
    int excl = woff + incl - s;
    sx[2 * t] = excl; sx[2 * t + 1] = excl + v0;
    __syncthreads();
    if (t < NB)       { boff[t] = sx[t];       bcur[t] = sx[t]; }
    if (t + 256 < NB) { boff[t + 256] = sx[t + 256]; bcur[t + 256] = sx[t + 256]; }
    if (t == 0) { boff[NB] = E; row_ptr[N] = E; }
}

__global__ __launch_bounds__(256) void bucket_bin_kernel(
    const int* __restrict__ rows, const int* __restrict__ cols, const float* __restrict__ val,
    int* __restrict__ bcur, int2* __restrict__ bcv, int E)
{
    __shared__ int hist[512], sx[512], cnt[512], gbase[512], wt[4];
    __shared__ int mb[4096];
    __shared__ int2 mcv[4096];
    int t = threadIdx.x;
    hist[t] = 0; hist[t + 256] = 0; cnt[t] = 0; cnt[t + 256] = 0;
    __syncthreads();
    int base = blockIdx.x * 4096;
    int r[16];
#pragma unroll
    for (int i = 0; i < 16; ++i) {
        int e = base + i * 256 + t;
        r[i] = (e < E) ? rows[e] : -1;
        if (r[i] >= 0) atomicAdd(&hist[r[i] >> BSH], 1);
    }
    __syncthreads();
    int v0 = hist[2 * t], v1 = hist[2 * t + 1];
    int s = v0 + v1, incl = s;
    for (int o = 1; o < 64; o <<= 1) { int u = __shfl_up(incl, o); if ((t & 63) >= o) incl += u; }
    if ((t & 63) == 63) wt[t >> 6] = incl;
    __syncthreads();
    int woff = 0, w = t >> 6;
    for (int i = 0; i < w; ++i) woff += wt[i];
    int excl = woff + incl - s;
    sx[2 * t] = excl; sx[2 * t + 1] = excl + v0;
    __syncthreads();
    for (int bb = t; bb < 512; bb += 256)
        if (hist[bb]) gbase[bb] = atomicAdd(&bcur[bb], hist[bb]);
    __syncthreads();
#pragma unroll
    for (int i = 0; i < 16; ++i) {
        if (r[i] < 0) continue;
        int e = base + i * 256 + t;
        int bb = r[i] >> BSH;
        int p = atomicAdd(&cnt[bb], 1);
        int loc = sx[bb] + p;
        mb[loc] = bb;
        int2 cv;
        cv.x = cols[e] | ((r[i] & (BROWS - 1)) << COLBITS);
        cv.y = __float_as_int(val[e]);
        mcv[loc] = cv;
    }
    __syncthreads();
    int Mv = sx[511] + hist[511];
    for (int loc = t; loc < Mv; loc += 256) {
        int bb = mb[loc];
        int gidx = gbase[bb] + (loc - sx[bb]);
        bcv[gidx] = mcv[loc];
    }
}

__global__ __launch_bounds__(256) void bucket_place_kernel(
    const int2* __restrict__ bcv, const int* __restrict__ boff, int* __restrict__ row_ptr,
    int2* __restrict__ cpack, int N)
{
    __shared__ int rcnt[512], sx[512], wt[4];
    int b = blockIdx.x;
    int t = threadIdx.x;
    rcnt[t] = 0; rcnt[t + 256] = 0;
    __syncthreads();
    int rbase = b << BSH;
    int rn = min(BROWS, N - rbase);
    int lo = boff[b], hi = boff[b + 1];
    for (int p = lo + t; p < hi; p += 256)
        atomicAdd(&rcnt[((unsigned)bcv[p].x) >> COLBITS], 1);
    __syncthreads();
    int v0 = rcnt[2 * t], v1 = rcnt[2 * t + 1];
    int s = v0 + v1, incl = s;
    for (int o = 1; o < 64; o <<= 1) { int u = __shfl_up(incl, o); if ((t & 63) >= o) incl += u; }
    if ((t & 63) == 63) wt[t >> 6] = incl;
    __syncthreads();
    int woff = 0, w = t >> 6;
    for (int i = 0; i < w; ++i) woff += wt[i];
    int excl = woff + incl - s;
    sx[2 * t] = excl; sx[2 * t + 1] = excl + v0;
    __syncthreads();
    if (t < rn)       row_ptr[rbase + t] = lo + sx[t];
    if (t + 256 < rn) row_ptr[rbase + t + 256] = lo + sx[t + 256];
    __syncthreads();
    sx[t] += lo; sx[t + 256] += lo;
    __syncthreads();
    for (int p = lo + t; p < hi; p += 256) {
        int2 cv = bcv[p];
        int rin = ((unsigned)cv.x) >> COLBITS;
        int slot = atomicAdd(&sx[rin], 1);
        cv.x &= (1 << COLBITS) - 1;
        cpack[slot] = cv;
    }
}

// ---------------- MFMA GEMM (fragment-packed W, XOR-swizzled X LDS) ----------------
template<int IN_BF16, int OUT_BF16, int ACT>
__global__ __launch_bounds__(256, 4) void gemm_mfma(
    const void* __restrict__ Xv, const bf16* __restrict__ Wf,
    const float* __restrict__ bias, void* __restrict__ Yv, int M, int Nout)
{
    __shared__ bf16 Xs[128 * 128];
    const int tid = threadIdx.x;
    const int rb = blockIdx.x * 128;
    const int cb = blockIdx.y * 128;
    const bf16* Wfb = Wf + (size_t)cb * CCH;

    if (IN_BF16) {
#pragma unroll
        for (int i = 0; i < 8; ++i) {
            int c = tid + i * 256;
            int r = c >> 4, kc = c & 15;
            int grow = rb + r;
            bf16x8 o = {};
            if (grow < M) o = *(const bf16x8*)&((const bf16*)Xv)[(size_t)grow * CCH + kc * 8];
            *(bf16x8*)&Xs[(r * 16 + (kc ^ (r & 15))) << 3] = o;
        }
    } else {
#pragma unroll
        for (int i = 0; i < 16; ++i) {
            int c = tid + i * 256;
            int r = c >> 5, sub = c & 31;
            int kc = sub >> 1, half = sub & 1;
            int grow = rb + r;
            bf16x4 o = {};
            if (grow < M) {
                float4 xv = *(const float4*)&((const float*)Xv)[(size_t)grow * CCH + kc * 8 + half * 4];
                o[0] = (bf16)xv.x; o[1] = (bf16)xv.y; o[2] = (bf16)xv.z; o[3] = (bf16)xv.w;
            }
            *(bf16x4*)&Xs[((r * 16 + (kc ^ (r & 15))) << 3) + half * 4] = o;
        }
    }
    __syncthreads();

    const int w = tid >> 6, lane = tid & 63;
    const int col16 = lane & 15, quad = lane >> 4;
    const int wm = (w & 1) * 64, wn = (w >> 1) * 64;

    f32x4 acc[4][4] = {};
#pragma unroll
    for (int kk = 0; kk < 4; ++kk) {
        const int kc = kk * 4 + quad;
        bf16x8 bfr[4], af[4];
#pragma unroll
        for (int ni = 0; ni < 4; ++ni)
            bfr[ni] = *(const bf16x8*)&Wfb[(size_t)((kc * 128 + wn + ni * 16 + col16) << 3)];
#pragma unroll
        for (int mi = 0; mi < 4; ++mi) {
            int r = wm + mi * 16 + col16;
            af[mi] = *(const bf16x8*)&Xs[(r * 16 + (kc ^ col16)) << 3];
        }
#pragma unroll
        for (int mi = 0; mi < 4; ++mi)
#pragma unroll
            for (int ni = 0; ni < 4; ++ni)
                acc[mi][ni] = __builtin_amdgcn_mfma_f32_16x16x32_bf16(af[mi], bfr[ni], acc[mi][ni], 0, 0, 0);
    }

#pragma unroll
    for (int mi = 0; mi < 4; ++mi) {
#pragma unroll
        for (int r = 0; r < 4; ++r) {
            int row = rb + wm + mi * 16 + quad * 4 + r;
            if (row >= M) continue;
#pragma unroll
            for (int ni = 0; ni < 4; ++ni) {
                int col = cb + wn + ni * 16 + col16;
                float vv = acc[mi][ni][r];
                if (bias) vv += bias[col];
                if (ACT == 1) vv = vv > 0.f ? vv : expm1f(vv);   // elu
                if (OUT_BF16) ((bf16*)Yv)[(size_t)row * Nout + col] = (bf16)vv;
                else          ((float*)Yv)[(size_t)row * Nout + col] = vv;
            }
        }
    }
}

// ---------------- fused dual-GEMM + GRU: 32-row tiles (625 blocks at NTT) ----------------
// block 256 = 4 waves, wave w covers cols [w*32, w*32+32); phases cb0->r, cb2->n, cb1->z,h.
template<int TT>
__global__ __launch_bounds__(256, 2) void gru_gemm_kernel(
    const bf16* __restrict__ Agi, const float* __restrict__ meanf,
    const bf16* __restrict__ Wih, const bf16* __restrict__ Whh,
    const float* __restrict__ bih, const float* __restrict__ bhh,
    const float* __restrict__ sc4, const float* __restrict__ sh4,
    void* __restrict__ out,
    const float* __restrict__ vsp2, const float* __restrict__ c02, float* __restrict__ scores,
    int M)
{
    __shared__ bf16 Xi[32 * 128];
    __shared__ bf16 Xh[32 * 128];
    __shared__ float sred[32];
    const int tid = threadIdx.x;
    const int rb = blockIdx.x * 32;

    if (TT && tid < 32) sred[tid] = 0.f;
    // stage Agi (bf16): 32 rows x 16 chunks = 512 chunks
#pragma unroll
    for (int i = 0; i < 2; ++i) {
        int c = tid + i * 256;
        int r = c >> 4, kc = c & 15;
        int grow = rb + r;
        bf16x8 o = {};
        if (grow < M) o = *(const bf16x8*)&Agi[(size_t)grow * CCH + kc * 8];
        *(bf16x8*)&Xi[(r * 16 + (kc ^ (r & 15))) << 3] = o;
    }
    // stage mean (fp32 -> bf16): 32 rows x 32 half-chunks = 1024
#pragma unroll
    for (int i = 0; i < 4; ++i) {
        int c = tid + i * 256;
        int r = c >> 5, sub = c & 31;
        int kc = sub >> 1, half = sub & 1;
        int grow = rb + r;
        bf16x4 o = {};
        if (grow < M) {
            float4 xv = *(const float4*)&meanf[(size_t)grow * CCH + kc * 8 + half * 4];
            o[0] = (bf16)xv.x; o[1] = (bf16)xv.y; o[2] = (bf16)xv.z; o[3] = (bf16)xv.w;
        }
        *(bf16x4*)&Xh[((r * 16 + (kc ^ (r & 15))) << 3) + half * 4] = o;
    }
    __syncthreads();

    const int w = tid >> 6, lane = tid & 63;
    const int col16 = lane & 15, quad = lane >> 4;

    f32x4 carry[2][2];   // r, then n, then output

    const int phase_cb[3] = {0, 2, 1};
#pragma unroll
    for (int ph = 0; ph < 3; ++ph) {
        const int cb = phase_cb[ph];
        const bf16* Wi_t = Wih + (size_t)cb * 16384;
        const bf16* Wh_t = Whh + (size_t)cb * 16384;
        f32x4 ai[2][2] = {};
        f32x4 ah[2][2] = {};
#pragma unroll
        for (int kk = 0; kk < 4; ++kk) {
            const int kc = kk * 4 + quad;
            bf16x8 bi_f[2], bh_f[2], xi_f[2], xh_f[2];
#pragma unroll
            for (int ni = 0; ni < 2; ++ni) {
                int wc = w * 32 + ni * 16 + col16;
                bi_f[ni] = *(const bf16x8*)&Wi_t[(size_t)((kc * 128 + wc) << 3)];
                bh_f[ni] = *(const bf16x8*)&Wh_t[(size_t)((kc * 128 + wc) << 3)];
            }
#pragma unroll
            for (int mi = 0; mi < 2; ++mi) {
                int r = mi * 16 + col16;
                xi_f[mi] = *(const bf16x8*)&Xi[(r * 16 + (kc ^ col16)) << 3];
                xh_f[mi] = *(const bf16x8*)&Xh[(r * 16 + (kc ^ col16)) << 3];
            }
#pragma unroll
            for (int mi = 0; mi < 2; ++mi)
#pragma unroll
                for (int ni = 0; ni < 2; ++ni) {
                    ai[mi][ni] = __builtin_amdgcn_mfma_f32_16x16x32_bf16(xi_f[mi], bi_f[ni], ai[mi][ni], 0, 0, 0);
                    ah[mi][ni] = __builtin_amdgcn_mfma_f32_16x16x32_bf16(xh_f[mi], bh_f[ni], ah[mi][ni], 0, 0, 0);
                }
        }
        const int gofs = cb * 128;
#pragma unroll
        for (int mi = 0; mi < 2; ++mi) {
#pragma unroll
            for (int ni = 0; ni < 2; ++ni) {
                int col = w * 32 + ni * 16 + col16;
                float bi_v = bih[gofs + col], bh_v = bhh[gofs + col];
#pragma unroll
                for (int rr = 0; rr < 4; ++rr) {
                    float vi = ai[mi][ni][rr] + bi_v;
                    float vh = ah[mi][ni][rr] + bh_v;
                    if (ph == 0) {
                        carry[mi][ni][rr] = 1.f / (1.f + __expf(-(vi + vh)));
                    } else if (ph == 1) {
                        carry[mi][ni][rr] = tanhf(vi + carry[mi][ni][rr] * vh);
                    } else {
                        float z = 1.f / (1.f + __expf(-(vi + vh)));
                        int row = rb + mi * 16 + quad * 4 + rr;
                        float mval = (row < M) ? meanf[(size_t)row * CCH + col] : 0.f;
                        float h = (1.f - z) * carry[mi][ni][rr] + z * mval;
                        h = fmaxf(h, 0.f);
                        carry[mi][ni][rr] = h * sc4[col] + sh4[col];
                    }
                }
            }
        }
    }

#pragma unroll
    for (int mi = 0; mi < 2; ++mi) {
#pragma unroll
        for (int rr = 0; rr < 4; ++rr) {
            int rloc = mi * 16 + quad * 4 + rr;
            int row = rb + rloc;
            float p = 0.f;
#pragma unroll
            for (int ni = 0; ni < 2; ++ni) {
                int col = w * 32 + ni * 16 + col16;
                float o = carry[mi][ni][rr];
                if (row < M) {
                    if (TT) ((bf16*)out)[(size_t)row * CCH + col] = (bf16)o;
                    else    ((float*)out)[(size_t)row * CCH + col] = o;
                }
                if (TT) p += o * vsp2[col];
            }
            if (TT && row < M) atomicAdd(&sred[rloc], p);
        }
    }
    if (TT) {
        __syncthreads();
        if (tid < 32 && rb + tid < M) scores[rb + tid] = sred[tid] + c02[0];
    }
}

// ---------------- SpMM (CSR gather): 16 lanes/row x bf16x8, 4-edge unroll ----------------
template<int SCORES>
__global__ __launch_bounds__(256) void spmm_csr_kernel(
    const int* __restrict__ row_ptr, const int2* __restrict__ cpack,
    const bf16* __restrict__ Xin, bf16* __restrict__ Y,
    const float* __restrict__ bvec, const float* __restrict__ sc, const float* __restrict__ sh,
    const float* __restrict__ vsp, const float* __restrict__ c0p, float* __restrict__ scores,
    int Nrow)
{
    int gid = blockIdx.x * 256 + threadIdx.x;
    int row = gid >> 4;
    if (row >= Nrow) return;
    int l8 = (gid & 15) << 3;
    int st = row_ptr[row], en = row_ptr[row + 1];
    float acc[8] = {};
    int j = st;
    for (; j + 4 <= en; j += 4) {
        int2 p0 = cpack[j], p1 = cpack[j + 1], p2 = cpack[j + 2], p3 = cpack[j + 3];
        bf16x8 x0 = *(const bf16x8*)&Xin[(size_t)p0.x * CCH + l8];
        bf16x8 x1 = *(const bf16x8*)&Xin[(size_t)p1.x * CCH + l8];
        bf16x8 x2 = *(const bf16x8*)&Xin[(size_t)p2.x * CCH + l8];
        bf16x8 x3 = *(const bf16x8*)&Xin[(size_t)p3.x * CCH + l8];
        float v0 = __int_as_float(p0.y), v1 = __int_as_float(p1.y);
        float v2 = __int_as_float(p2.y), v3 = __int_as_float(p3.y);
#pragma unroll
        for (int q = 0; q < 8; ++q)
            acc[q] += v0 * (float)x0[q] + v1 * (float)x1[q] + v2 * (float)x2[q] + v3 * (float)x3[q];
    }
    if (j + 2 <= en) {
        int2 p0 = cpack[j], p1 = cpack[j + 1];
        bf16x8 x0 = *(const bf16x8*)&Xin[(size_t)p0.x * CCH + l8];
        bf16x8 x1 = *(const bf16x8*)&Xin[(size_t)p1.x * CCH + l8];
        float v0 = __int_as_float(p0.y), v1 = __int_as_float(p1.y);
#pragma unroll
        for (int q = 0; q < 8; ++q) acc[q] += v0 * (float)x0[q] + v1 * (float)x1[q];
        j += 2;
    }
    if (j < en) {
        int2 p0 = cpack[j];
        bf16x8 x0 = *(const bf16x8*)&Xin[(size_t)p0.x * CCH + l8];
        float v0 = __int_as_float(p0.y);
#pragma unroll
        for (int q = 0; q < 8; ++q) acc[q] += v0 * (float)x0[q];
    }
    float o[8];
    bf16x8 ov;
#pragma unroll
    for (int q = 0; q < 8; ++q) {
        o[q] = fmaxf((acc[q] + bvec[l8 + q]) * sc[l8 + q] + sh[l8 + q], 0.f);
        ov[q] = (bf16)o[q];
    }
    *(bf16x8*)&Y[(size_t)row * CCH + l8] = ov;
    if (SCORES) {
        float p = 0.f;
#pragma unroll
        for (int q = 0; q < 8; ++q) p += o[q] * vsp[l8 + q];
        for (int d = 8; d; d >>= 1) p += __shfl_down(p, d, 16);
        if ((gid & 15) == 0) scores[row] = p + c0p[0];
    }
}

// ---------------- fused pool + attention pool (per segment) ----------------
__global__ __launch_bounds__(128) void segstage_kernel(
    const bf16* __restrict__ X, const float* __restrict__ sarr, const int* __restrict__ starts,
    const float* __restrict__ sc2, const float* __restrict__ sh2,
    const float* __restrict__ sc3, const float* __restrict__ sh3,
    const float* __restrict__ vd, float* __restrict__ mean, bf16* __restrict__ upool)
{
    __shared__ float red[2];
    __shared__ float adsh;
    int t = blockIdx.x;
    int c = threadIdx.x;
    int st = starts[t], en = starts[t + 1];
    float sum = 0.f;
    for (int i = st; i < en; ++i) sum += (float)X[(size_t)i * CCH + c];
    float cnt = (float)(en - st);
    float poolb = fmaxf(sum * sc2[c] + cnt * sh2[c], 0.f);
    float mv = poolb * sc3[c] + sh3[c];
    mean[(size_t)t * CCH + c] = mv;
    float p = mv * vd[c];
    for (int o = 32; o; o >>= 1) p += __shfl_down(p, o);
    if ((c & 63) == 0) red[c >> 6] = p;
    __syncthreads();
    if (c == 0) adsh = red[0] + red[1];
    __syncthreads();
    if (en == st) { upool[(size_t)t * CCH + c] = (bf16)0.f; return; }
    float adt = adsh;
    float lm = -3.0e38f;
    for (int i = st + c; i < en; i += 128) {
        float a = sarr[i] + adt;
        a = a > 0.f ? a : 0.01f * a;
        lm = fmaxf(lm, a);
    }
    for (int o = 32; o; o >>= 1) lm = fmaxf(lm, __shfl_down(lm, o));
    if ((c & 63) == 0) red[c >> 6] = lm;
    __syncthreads();
    float m = fmaxf(red[0], red[1]);
    float u = 0.f, den = 0.f;
    for (int i = st; i < en; ++i) {
        float a = sarr[i] + adt;
        a = a > 0.f ? a : 0.01f * a;
        float e = __expf(a - m);
        den += e;
        u += e * (float)X[(size_t)i * CCH + c];
    }
    upool[(size_t)t * CCH + c] = (bf16)((u / den) * sc2[c] + sh2[c]);
}

// predictor: one block (64 thr) per molecule
__global__ __launch_bounds__(64) void pred_kernel(
    const float* __restrict__ mol, const float* __restrict__ pW1, const float* __restrict__ pb1,
    const float* __restrict__ pW2, const float* __restrict__ pb2, float* __restrict__ out)
{
    __shared__ float row[CCH];
    int m = blockIdx.x;
    int j = threadIdx.x;
    row[j] = mol[(size_t)m * CCH + j];
    row[j + 64] = mol[(size_t)m * CCH + 64 + j];
    __syncthreads();
    float h = pb1[j];
#pragma unroll
    for (int k = 0; k < CCH; ++k) h += row[k] * pW1[j * CCH + k];
    h = fmaxf(h, 0.f);
    float p = h * pW2[j];
    for (int o = 32; o; o >>= 1) p += __shfl_down(p, o);
    if (j == 0) out[m] = p + pb2[0];
}

// ---------------- host ----------------

extern "C" void kernel_launch(void* const* d_in, const int* in_sizes, int n_in,
                              void* d_out, int out_size, void* d_ws, size_t ws_size,
                              hipStream_t stream)
{
    (void)n_in; (void)ws_size;
    const float* node_attr      = (const float*)d_in[0];
    const int*   adj_index      = (const int*)  d_in[1];
    const float* adj_value      = (const float*)d_in[2];
    const int*   tt_node_batch  = (const int*)  d_in[3];
    const int*   tt_graph_batch = (const int*)  d_in[4];
    const float* W_gcn    = (const float*)d_in[5];
    const float* b_gcn    = (const float*)d_in[6];
    const float* bn_gamma = (const float*)d_in[7];
    const float* bn_beta  = (const float*)d_in[8];
    const float* bn_mean  = (const float*)d_in[9];
    const float* bn_var   = (const float*)d_in[10];
    const float* gat_Wsrc = (const float*)d_in[11];
    const float* gat_Wdst = (const float*)d_in[12];
    const float* gat_asrc = (const float*)d_in[13];
    const float* gat_adst = (const float*)d_in[14];
    const float* gat_bias = (const float*)d_in[15];
    const float* gru_Wih  = (const float*)d_in[16];
    const float* gru_Whh  = (const float*)d_in[17];
    const float* gru_bih  = (const float*)d_in[18];
    const float* gru_bhh  = (const float*)d_in[19];
    const float* pW1 = (const float*)d_in[20];
    const float* pb1 = (const float*)d_in[21];
    const float* pW2 = (const float*)d_in[22];
    const float* pb2 = (const float*)d_in[23];

    const int E    = in_sizes[2];
    const int N    = in_sizes[3];
    const int NTT  = in_sizes[4];
    const int NMOL = out_size;
    const int NB   = (N + BROWS - 1) >> BSH;

    const int* adj_rows = adj_index;
    const int* adj_cols = adj_index + E;

    // ---- workspace carve ----
    char* wsb = (char*)d_ws;
    size_t off = 0;
    auto carve = [&](size_t bytes) -> char* {
        char* p = wsb + off;
        off = (off + bytes + 255) & ~(size_t)255;
        return p;
    };
    bf16* bufB = (bf16*)carve((size_t)N * CCH * 2);
    bf16* bufA = (bf16*)carve((size_t)N * CCH * 2);
    bf16* tt   = (bf16*)carve((size_t)NTT * CCH * 2);
    float* mol  = (float*)carve((size_t)NMOL * CCH * 4);
    float* mean  = (float*)carve((size_t)NTT * CCH * 4);
    bf16*  upool = (bf16*)carve((size_t)NTT * CCH * 2);
    bf16*  gbuf  = (bf16*)carve((size_t)NTT * CCH * 2);
    float* scores = (float*)carve((size_t)N * 4);
    int* starts_tt  = (int*)carve((size_t)(NTT + 1) * 4);
    int* starts_mol = (int*)carve((size_t)(NMOL + 1) * 4);
    float* bnsc = (float*)carve(8 * CCH * 4);
    float* bnsh = (float*)carve(8 * CCH * 4);
    float* vsp  = (float*)carve(2 * CCH * 4);
    float* vd   = (float*)carve(2 * CCH * 4);
    float* c0   = (float*)carve(2 * 4);
    bf16* Wgcnb = (bf16*)carve((size_t)2 * CCH * CCH * 2);
    bf16* Wsrcb = (bf16*)carve((size_t)2 * CCH * CCH * 2);
    bf16* Wihb  = (bf16*)carve((size_t)2 * G3 * CCH * 2);
    bf16* Whhb  = (bf16*)carve((size_t)2 * G3 * CCH * 2);
    int*   bhist   = (int*)carve(512 * 4);
    int*   boff    = (int*)carve((size_t)(NB + 1) * 4);
    int*   bcur    = (int*)carve((size_t)NB * 4);
    int*   row_ptr = (int*)carve((size_t)(N + 1) * 4);
    int2*  bcv     = (int2*)carve((size_t)E * 8);
    int2*  cpack   = (int2*)carve((size_t)E * 8);

    // ---- fused prep ----
    const int B1 = 4;
    const int B2 = B1 + 2;
    const int B3 = B2 + (NTT + 1 + 255) / 256;
    const int B4 = B3 + (NMOL + 1 + 255) / 256;
    const int B5 = B4 + 1;
    const int B6 = B5 + 16;
    const int B7 = B6 + 16;
    const int B8 = B7 + 48;
    const int B9 = B8 + 48;
    prep_kernel<<<B9, 256, 0, stream>>>(
        bn_gamma, bn_beta, bn_mean, bn_var, bnsc, bnsh,
        gat_Wsrc, gat_Wdst, gat_asrc, gat_adst, vsp, vd, c0,
        tt_node_batch, N, NTT, starts_tt,
        tt_graph_batch, NMOL, starts_mol,
        bhist,
        W_gcn, Wgcnb, Wsrcb, gru_Wih, Wihb, gru_Whh, Whhb,
        B1, B2, B3, B4, B5, B6, B7, B8);

    // ---- CSR build ----
    const int nchunk = (E + 4095) / 4096;
    bucket_hist_kernel<<<nchunk, 256, 0, stream>>>(adj_rows, bhist, E);
    bucket_scan_kernel<<<1, 256, 0, stream>>>(bhist, boff, bcur, row_ptr, NB, N, E);
    bucket_bin_kernel<<<nchunk, 256, 0, stream>>>(adj_rows, adj_cols, adj_value, bcur, bcv, E);
    bucket_place_kernel<<<NB, 256, 0, stream>>>(bcv, boff, row_ptr, cpack, N);

    // ---- GCN x2 ----
    dim3 gg((N + 127) / 128, 1);
    const int spmm_blocks = ((size_t)N * 16 + 255) / 256;
    gemm_mfma<0, 1, 0><<<gg, 256, 0, stream>>>(node_attr, Wgcnb, nullptr, bufB, N, CCH);
    spmm_csr_kernel<0><<<spmm_blocks, 256, 0, stream>>>(
        row_ptr, cpack, bufB, bufA, b_gcn, bnsc, bnsh, nullptr, nullptr, nullptr, N);
    gemm_mfma<1, 1, 0><<<gg, 256, 0, stream>>>(bufA, Wgcnb + CCH * CCH, nullptr, bufB, N, CCH);
    spmm_csr_kernel<1><<<spmm_blocks, 256, 0, stream>>>(
        row_ptr, cpack, bufB, bufA, b_gcn + CCH, bnsc + CCH, bnsh + CCH,
        vsp, c0, scores, N);

    // ---- tt stage: N -> NTT (fused GRU-GEMM, bf16 out + mol-stage scores) ----
    {
        const int bnb = 2, gi = 0, nseg = NTT;
        segstage_kernel<<<nseg, 128, 0, stream>>>(bufA, scores, starts_tt,
            bnsc + bnb * CCH, bnsh + bnb * CCH, bnsc + (bnb + 1) * CCH, bnsh + (bnb + 1) * CCH,
            vd + gi * CCH, mean, upool);
        dim3 g1((nseg + 127) / 128, 1);
        gemm_mfma<1, 1, 1><<<g1, 256, 0, stream>>>(upool, Wsrcb + gi * CCH * CCH,
                                                   gat_bias + gi * CCH, gbuf, nseg, CCH);
        gru_gemm_kernel<1><<<(nseg + 31) / 32, 256, 0, stream>>>(
            gbuf, mean, Wihb + gi * G3 * CCH, Whhb + gi * G3 * CCH,
            gru_bih + gi * G3, gru_bhh + gi * G3,
            bnsc + (bnb + 2) * CCH, bnsh + (bnb + 2) * CCH,
            tt, vsp + CCH, c0 + 1, scores, nseg);
    }

    // ---- mol stage: NTT -> NMOL (fused GRU-GEMM, fp32 out) + predictor ----
    {
        const int bnb = 5, gi = 1, nseg = NMOL;
        segstage_kernel<<<nseg, 128, 0, stream>>>(tt, scores, starts_mol,
            bnsc + bnb * CCH, bnsh + bnb * CCH, bnsc + (bnb + 1) * CCH, bnsh + (bnb + 1) * CCH,
            vd + gi * CCH, mean, upool);
        dim3 g1((nseg + 127) / 128, 1);
        gemm_mfma<1, 1, 1><<<g1, 256, 0, stream>>>(upool, Wsrcb + gi * CCH * CCH,
                                                   gat_bias + gi * CCH, gbuf, nseg, CCH);
        gru_gemm_kernel<0><<<(nseg + 31) / 32, 256, 0, stream>>>(
            gbuf, mean, Wihb + gi * G3 * CCH, Whhb + gi * G3 * CCH,
            gru_bih + gi * G3, gru_bhh + gi * G3,
            bnsc + (bnb + 2) * CCH, bnsh + (bnb + 2) * CCH,
            mol, nullptr, nullptr, nullptr, nseg);
        pred_kernel<<<NMOL, 64, 0, stream>>>(mol, pW1, pb1, pW2, pb2, (float*)d_out);
    }
}